// Round 2
// baseline (629.371 us; speedup 1.0000x reference)
//
#include <hip/hip_runtime.h>

#define N_NODES 100000
#define N_EDGES 20000
#define N_INC   800000
#define D_IN    256
#define D_H     16
#define D_OUT   40

// bucket geometry (identical to the proven round-0 partitioner)
#define EB_SHIFT 6
#define EB_SIZE  64
#define NBE      313          // ceil(20000/64)
#define ECAP     3200         // records per edge-bucket (mean 2560, +12.7 sigma)
#define VB_SHIFT 9
#define VB_SIZE  512
#define NBV      196          // ceil(100000/512)
#define VCAP     4800         // records per node-bucket (mean 4096, +11 sigma)
#define TE2      4096         // partition edge tile
#define TV2      6144         // partition node tile
#define EPART2   196          // ceil(800000/4096)
#define NPART2   131          // ceil(800000/6144)

#define GEMM_WAVES (N_NODES / 16)   // 6250
#define GEMM_BLOCKS 782             // ceil(6250/8) at 512 thr = 8 waves/blk

typedef short bf16x8 __attribute__((ext_vector_type(8)));
typedef float f32x4  __attribute__((ext_vector_type(4)));

__device__ __forceinline__ unsigned short f2bf(float f) {
    unsigned u = __float_as_uint(f);
    unsigned r = u + 0x7FFF + ((u >> 16) & 1);   // round-to-nearest-even
    return (unsigned short)(r >> 16);
}

// ---------------- K0: pack W1 into MFMA B-frag layout; zero bucket counters ----
__global__ __launch_bounds__(512) void init_kernel(
    const float* __restrict__ W1, unsigned short* __restrict__ bfrag,
    int* __restrict__ cnts /* cnt_be(320) ++ cnt_bv(320) */) {
    int t = threadIdx.x;
    for (int i = t; i < 640; i += 512) cnts[i] = 0;
    int c = t >> 6, l = t & 63;      // 512 threads = 8 chunks x 64 lanes
    int n = l & 15, q = l >> 4;
    unsigned short v[8];
#pragma unroll
    for (int j = 0; j < 8; ++j)
        v[j] = f2bf(W1[(c * 32 + q * 8 + j) * D_H + n]);
    *(int4*)(bfrag + (size_t)(c * 64 + l) * 8) = *(int4*)v;
}

// ---------------- K1: partition (LDS-staged, run-contiguous writes) || GEMM ----
union SMemP {
    struct { int2 lrec[TE2]; int lhist[NBE]; int lbase[NBE];
             int gbase[NBE]; int lcur[NBE]; int sc[512]; } pe;
    struct { int  lrec[TV2]; int lhist[NBV]; int lbase[NBV];
             int gbase[NBV]; int lcur[NBV]; int sc[512]; } pn;
};

__global__ __launch_bounds__(512) void part_gemm_kernel(
    const int* __restrict__ ni, const int* __restrict__ ei, const float* __restrict__ w,
    int* __restrict__ cnt_be, int* __restrict__ cnt_bv,
    int2* __restrict__ staged_e, int* __restrict__ staged_v,
    const float* __restrict__ H, const unsigned short* __restrict__ bfrag,
    float* __restrict__ T) {
    __shared__ SMemP sm;
    int t = threadIdx.x;
    if (blockIdx.x < EPART2) {
        int base = blockIdx.x * TE2;
        for (int i = t; i < NBE; i += 512) sm.pe.lhist[i] = 0;
        __syncthreads();
#pragma unroll
        for (int r = 0; r < TE2 / 512; ++r) {
            int idx = base + r * 512 + t;
            if (idx < N_INC) atomicAdd(&sm.pe.lhist[ei[idx] >> EB_SHIFT], 1);
        }
        __syncthreads();
        int h = (t < NBE) ? sm.pe.lhist[t] : 0;
        sm.pe.sc[t] = h; __syncthreads();
        for (int o = 1; o < 512; o <<= 1) {
            int x = (t >= o) ? sm.pe.sc[t - o] : 0; __syncthreads();
            sm.pe.sc[t] += x; __syncthreads();
        }
        if (t < NBE) {
            int ex = sm.pe.sc[t] - h;
            sm.pe.lbase[t] = ex; sm.pe.lcur[t] = ex;
            sm.pe.gbase[t] = h ? (t * ECAP + atomicAdd(&cnt_be[t], h)) : 0;
        }
        __syncthreads();
#pragma unroll
        for (int r = 0; r < TE2 / 512; ++r) {
            int idx = base + r * 512 + t;
            if (idx < N_INC) {
                int e = ei[idx], v = ni[idx];
                int key = e >> EB_SHIFT;
                int2 rec;
                rec.x = v | ((e & (EB_SIZE - 1)) << 17) | (key << 23);
                rec.y = __float_as_int(w[v]);
                int p = atomicAdd(&sm.pe.lcur[key], 1);
                sm.pe.lrec[p] = rec;
            }
        }
        __syncthreads();
        int total = min(TE2, N_INC - base);
        for (int i = t; i < total; i += 512) {
            int2 rec = sm.pe.lrec[i];
            int bk = ((unsigned)rec.x) >> 23;
            int dst = sm.pe.gbase[bk] + (i - sm.pe.lbase[bk]);
            if (dst < (bk + 1) * ECAP) staged_e[dst] = rec;
        }
    } else if (blockIdx.x < EPART2 + NPART2) {
        int base = (blockIdx.x - EPART2) * TV2;
        for (int i = t; i < NBV; i += 512) sm.pn.lhist[i] = 0;
        __syncthreads();
#pragma unroll
        for (int r = 0; r < TV2 / 512; ++r) {
            int idx = base + r * 512 + t;
            if (idx < N_INC) atomicAdd(&sm.pn.lhist[ni[idx] >> VB_SHIFT], 1);
        }
        __syncthreads();
        int h = (t < NBV) ? sm.pn.lhist[t] : 0;
        sm.pn.sc[t] = h; __syncthreads();
        for (int o = 1; o < 512; o <<= 1) {
            int x = (t >= o) ? sm.pn.sc[t - o] : 0; __syncthreads();
            sm.pn.sc[t] += x; __syncthreads();
        }
        if (t < NBV) {
            int ex = sm.pn.sc[t] - h;
            sm.pn.lbase[t] = ex; sm.pn.lcur[t] = ex;
            sm.pn.gbase[t] = h ? (t * VCAP + atomicAdd(&cnt_bv[t], h)) : 0;
        }
        __syncthreads();
#pragma unroll
        for (int r = 0; r < TV2 / 512; ++r) {
            int idx = base + r * 512 + t;
            if (idx < N_INC) {
                int e = ei[idx], v = ni[idx];
                int key = v >> VB_SHIFT;
                int rec = e | ((v & (VB_SIZE - 1)) << 15) | (key << 24);
                int p = atomicAdd(&sm.pn.lcur[key], 1);
                sm.pn.lrec[p] = rec;
            }
        }
        __syncthreads();
        int total = min(TV2, N_INC - base);
        for (int i = t; i < total; i += 512) {
            int rec = sm.pn.lrec[i];
            int bk = ((unsigned)rec) >> 24;
            int dst = sm.pn.gbase[bk] + (i - sm.pn.lbase[bk]);
            if (dst < (bk + 1) * VCAP) staged_v[dst] = rec;
        }
    } else {
        // ---- GEMM: T = H @ W1 via MFMA, one wave per 16x16 output tile ----
        int wave = ((blockIdx.x - EPART2 - NPART2) * 512 + t) >> 6;
        if (wave >= GEMM_WAVES) return;          // wave-uniform guard
        int lane = t & 63;
        int m = lane & 15, q = lane >> 4;
        int row0 = wave * 16;
        const float* hp = H + (size_t)(row0 + m) * D_IN + q * 8;

        bf16x8 bf[8];
        const int4* bp = (const int4*)bfrag;
#pragma unroll
        for (int c = 0; c < 8; ++c) {
            int4 raw = bp[c * 64 + lane];
            bf[c] = *(bf16x8*)&raw;
        }
        f32x4 acc = {0.f, 0.f, 0.f, 0.f};
#pragma unroll
        for (int c = 0; c < 8; ++c) {
            float4 lo = *(const float4*)(hp + c * 32);
            float4 hi = *(const float4*)(hp + c * 32 + 4);
            bf16x8 af;
            af[0] = f2bf(lo.x); af[1] = f2bf(lo.y); af[2] = f2bf(lo.z); af[3] = f2bf(lo.w);
            af[4] = f2bf(hi.x); af[5] = f2bf(hi.y); af[6] = f2bf(hi.z); af[7] = f2bf(hi.w);
            acc = __builtin_amdgcn_mfma_f32_16x16x32_bf16(af, bf[c], acc, 0, 0, 0);
        }
        // C/D layout: col = lane&15, row = q*4 + reg
#pragma unroll
        for (int r = 0; r < 4; ++r)
            T[(size_t)(row0 + q * 4 + r) * D_H + m] = acc[r];
    }
}

// ---------------- gatherA: one block per edge-bucket (64 edges) -----------------
// Stage bucket records in LDS, route rows into eacc[64][16] via LDS f32 atomics.
__global__ __launch_bounds__(512) void gatherA_bucket_kernel(
    const int* __restrict__ cnt_be, const int2* __restrict__ staged_e,
    const float* __restrict__ X, float* __restrict__ e_feat) {
    __shared__ int2  srec[ECAP];          // 25.6 KB
    __shared__ float eacc[64 * 16];       // 4 KB
    __shared__ float eden[64];
    int b = blockIdx.x, t = threadIdx.x;
    int cnt = min(cnt_be[b], ECAP);
    for (int i = t; i < 64 * 16; i += 512) eacc[i] = 0.f;
    if (t < 64) eden[t] = 0.f;
    const int2* gp = staged_e + (size_t)b * ECAP;
    for (int i = t; i < cnt; i += 512) srec[i] = gp[i];
    __syncthreads();
    int c = (t & 3) * 4;                  // 4 lanes per record, float4 each
#pragma unroll 2
    for (int r = t >> 2; r < cnt; r += 128) {
        int2 rec = srec[r];
        int v = rec.x & 0x1FFFF;
        int el = (rec.x >> 17) & 63;
        float wv = __int_as_float(rec.y);
        float4 x = *(const float4*)(X + (size_t)v * D_H + c);
        atomicAdd(&eacc[el * 16 + c],     x.x * wv);
        atomicAdd(&eacc[el * 16 + c + 1], x.y * wv);
        atomicAdd(&eacc[el * 16 + c + 2], x.z * wv);
        atomicAdd(&eacc[el * 16 + c + 3], x.w * wv);
        if (c == 0) atomicAdd(&eden[el], wv);
    }
    __syncthreads();
    for (int i = t; i < 64 * 16; i += 512) {
        int e = b * EB_SIZE + (i >> 4);
        if (e < N_EDGES)
            e_feat[(size_t)e * D_H + (i & 15)] = eacc[i] / fmaxf(eden[i >> 4], 1e-6f);
    }
}

// ---------------- gatherB layer 1: one block per node-bucket (512 nodes) --------
__global__ __launch_bounds__(512) void gatherB1_bucket_kernel(
    const int* __restrict__ cnt_bv, const int* __restrict__ staged_v,
    const float* __restrict__ e_feat,
    const float* __restrict__ b1, float* __restrict__ out) {
    __shared__ int   srec[VCAP];          // 19.2 KB
    __shared__ float vacc[512 * 17];      // 34.8 KB (stride 17: bank-conflict-free)
    __shared__ float vdeg[512];
    int b = blockIdx.x, t = threadIdx.x;
    int cnt = min(cnt_bv[b], VCAP);
    for (int i = t; i < 512 * 17; i += 512) vacc[i] = 0.f;
    vdeg[t] = 0.f;
    const int* gp = staged_v + (size_t)b * VCAP;
    for (int i = t; i < cnt; i += 512) srec[i] = gp[i];
    __syncthreads();
    int c = (t & 3) * 4;
#pragma unroll 2
    for (int r = t >> 2; r < cnt; r += 128) {
        int rec = srec[r];
        int e = rec & 0x7FFF;
        int vl = (rec >> 15) & 511;
        float4 f = *(const float4*)(e_feat + (size_t)e * D_H + c);
        atomicAdd(&vacc[vl * 17 + c],     f.x);
        atomicAdd(&vacc[vl * 17 + c + 1], f.y);
        atomicAdd(&vacc[vl * 17 + c + 2], f.z);
        atomicAdd(&vacc[vl * 17 + c + 3], f.w);
        if (c == 0) atomicAdd(&vdeg[vl], 1.f);
    }
    __syncthreads();
    for (int i = t; i < 512 * 16; i += 512) {
        int vl = i >> 4, j = i & 15;
        int n = b * VB_SIZE + vl;
        if (n < N_NODES) {
            float inv = 1.f / fmaxf(vdeg[vl], 1.f);
            out[(size_t)n * D_H + j] = fmaxf(vacc[vl * 17 + j] * inv + b1[j], 0.f);
        }
    }
}

// ---------------- gatherB layer 2 + W2 matmul + log_softmax fused ---------------
__global__ __launch_bounds__(512) void gatherB2_final_kernel(
    const int* __restrict__ cnt_bv, const int* __restrict__ staged_v,
    const float* __restrict__ e_feat,
    const float* __restrict__ W2, const float* __restrict__ b2,
    float* __restrict__ out) {
    __shared__ int   srec[VCAP];
    __shared__ float vacc[512 * 17];
    __shared__ float vdeg[512];
    __shared__ float sW2[D_H * D_OUT];
    __shared__ float sb2[D_OUT];
    int b = blockIdx.x, t = threadIdx.x;
    for (int i = t; i < D_H * D_OUT; i += 512) sW2[i] = W2[i];
    if (t < D_OUT) sb2[t] = b2[t];
    int cnt = min(cnt_bv[b], VCAP);
    for (int i = t; i < 512 * 17; i += 512) vacc[i] = 0.f;
    vdeg[t] = 0.f;
    const int* gp = staged_v + (size_t)b * VCAP;
    for (int i = t; i < cnt; i += 512) srec[i] = gp[i];
    __syncthreads();
    int c = (t & 3) * 4;
#pragma unroll 2
    for (int r = t >> 2; r < cnt; r += 128) {
        int rec = srec[r];
        int e = rec & 0x7FFF;
        int vl = (rec >> 15) & 511;
        float4 f = *(const float4*)(e_feat + (size_t)e * D_H + c);
        atomicAdd(&vacc[vl * 17 + c],     f.x);
        atomicAdd(&vacc[vl * 17 + c + 1], f.y);
        atomicAdd(&vacc[vl * 17 + c + 2], f.z);
        atomicAdd(&vacc[vl * 17 + c + 3], f.w);
        if (c == 0) atomicAdd(&vdeg[vl], 1.f);
    }
    __syncthreads();
    int n = b * VB_SIZE + t;
    if (n >= N_NODES) return;
    float inv = 1.f / fmaxf(vdeg[t], 1.f);
    float y[D_H];
#pragma unroll
    for (int jj = 0; jj < D_H; ++jj) y[jj] = vacc[t * 17 + jj] * inv;
    float z[D_OUT];
#pragma unroll
    for (int cc = 0; cc < D_OUT; ++cc) z[cc] = sb2[cc];
#pragma unroll
    for (int jj = 0; jj < D_H; ++jj) {
        float yy = y[jj];
#pragma unroll
        for (int cc = 0; cc < D_OUT; ++cc) z[cc] += yy * sW2[jj * D_OUT + cc];
    }
    float m = z[0];
#pragma unroll
    for (int cc = 1; cc < D_OUT; ++cc) m = fmaxf(m, z[cc]);
    float se = 0.f;
#pragma unroll
    for (int cc = 0; cc < D_OUT; ++cc) se += __expf(z[cc] - m);
    float lse = m + __logf(se);
    float* op = out + (size_t)n * D_OUT;
#pragma unroll
    for (int cc = 0; cc < D_OUT; ++cc) op[cc] = z[cc] - lse;
}

extern "C" void kernel_launch(void* const* d_in, const int* in_sizes, int n_in,
                              void* d_out, int out_size, void* d_ws, size_t ws_size,
                              hipStream_t stream) {
    const float* H  = (const float*)d_in[0];
    const float* w  = (const float*)d_in[1];
    const int*   ni = (const int*)d_in[2];
    const int*   ei = (const int*)d_in[3];
    const float* W1 = (const float*)d_in[4];
    const float* b1 = (const float*)d_in[5];
    const float* W2 = (const float*)d_in[6];
    const float* b2 = (const float*)d_in[7];
    float* out = (float*)d_out;

    // workspace layout (4-byte words)
    int*            ws_i     = (int*)d_ws;
    int*            cnt_be   = ws_i + 0;                      // 320
    int*            cnt_bv   = ws_i + 320;                    // 320
    unsigned short* bfrag    = (unsigned short*)(ws_i + 640); // 4096 ush = 2048 w
    int2*           staged_e = (int2*)(ws_i + 2688);          // 313*3200 int2
    int*            staged_v = ws_i + 2005888;                // 196*4800
    float*          T        = (float*)(ws_i + 2946688);      // 1,600,000
    float*          e_feat   = (float*)(ws_i + 4546688);      // 320,000
    float*          x1       = (float*)(ws_i + 4866688);      // 1,600,000
    // total 6,466,688 words = 25.9 MB

    init_kernel<<<1, 512, 0, stream>>>(W1, bfrag, cnt_be);

    part_gemm_kernel<<<EPART2 + NPART2 + GEMM_BLOCKS, 512, 0, stream>>>(
        ni, ei, w, cnt_be, cnt_bv, staged_e, staged_v, H, bfrag, T);

    // layer 1
    gatherA_bucket_kernel<<<NBE, 512, 0, stream>>>(cnt_be, staged_e, T, e_feat);
    gatherB1_bucket_kernel<<<NBV, 512, 0, stream>>>(cnt_bv, staged_v, e_feat, b1, x1);
    // layer 2 (+ final matmul + log_softmax fused)
    gatherA_bucket_kernel<<<NBE, 512, 0, stream>>>(cnt_be, staged_e, x1, e_feat);
    gatherB2_final_kernel<<<NBV, 512, 0, stream>>>(cnt_bv, staged_v, e_feat, W2, b2, out);
}

// Round 3
// 387.183 us; speedup vs baseline: 1.6255x; 1.6255x over previous
//
#include <hip/hip_runtime.h>

#define N_NODES 100000
#define N_EDGES 20000
#define N_INC   800000
#define D_IN    256
#define D_H     16
#define D_OUT   40

// per-edge / per-node fixed-capacity buckets, direct atomic scatter with
// XCD-ownership filtering (owner = key&7 == blockIdx&7) so bucket frontier
// lines stay resident in one XCD's L2 (round-1 failure mode: cross-XCD
// line ping-pong, WRITE_SIZE 106MB).
// edge degree ~ Poisson(40): P(deg>=96)*20k ~ 4e-3  -> ECAP 96 (384B)
// node degree ~ Poisson(8):  P(deg>=32)*100k ~ 1e-5 -> VCAP 32 (128B = 1 line)
#define ECAP 96
#define VCAP 32

#define SCAT_GROUPS 8
#define SCAT_BPG    64     // blocks per owner group
#define SCAT_BLOCKS (SCAT_GROUPS * SCAT_BPG)   // 512
#define SCAT_STRIDE (SCAT_BPG * 256)           // 16384 threads per group
#define GEMM_BLOCKS 1563   // ceil(6250 waves / 4 waves-per-256-thr-block)

typedef short bf16x8 __attribute__((ext_vector_type(8)));
typedef float f32x4  __attribute__((ext_vector_type(4)));

__device__ __forceinline__ unsigned short f2bf(float f) {
    unsigned u = __float_as_uint(f);
    unsigned r = u + 0x7FFF + ((u >> 16) & 1);   // round-to-nearest-even
    return (unsigned short)(r >> 16);
}

// ---------------- K0: pack W1 into MFMA B-frag layout; zero counters -----------
// counters: cnt_e(20000) ++ cnt_v(100000) ++ e_den(20000) contiguous = 140000
__global__ __launch_bounds__(512) void init_kernel(
    const float* __restrict__ W1, unsigned short* __restrict__ bfrag,
    int* __restrict__ cnts) {
    int g = blockIdx.x * 512 + threadIdx.x;
    for (int i = g; i < 140000; i += gridDim.x * 512) cnts[i] = 0;
    if (blockIdx.x == 0) {
        int t = threadIdx.x;
        int c = t >> 6, l = t & 63;      // 512 threads = 8 chunks x 64 lanes
        int n = l & 15, q = l >> 4;
        unsigned short v[8];
#pragma unroll
        for (int j = 0; j < 8; ++j)
            v[j] = f2bf(W1[(c * 32 + q * 8 + j) * D_H + n]);
        *(int4*)(bfrag + (size_t)(c * 64 + l) * 8) = *(int4*)v;
    }
}

// ---------------- K1: XCD-filtered incidence scatter || GEMM (T = H@W1 · w) ----
// scatter blocks first (blockIdx 0..511) so owner = blockIdx&7 lines up with the
// round-robin block->XCD mapping; GEMM streaming blocks fill the machine after.
__global__ __launch_bounds__(256) void scat_gemm_kernel(
    const int* __restrict__ ni, const int* __restrict__ ei,
    const float* __restrict__ w,
    int* __restrict__ cnt_e, int* __restrict__ cnt_v, float* __restrict__ e_den,
    int* __restrict__ staged_e, int* __restrict__ staged_v,
    const float* __restrict__ H, const unsigned short* __restrict__ bfrag,
    float* __restrict__ T) {
    if (blockIdx.x < SCAT_BLOCKS) {
        int owner = blockIdx.x & 7;
        int bi = blockIdx.x >> 3;
        for (int i = bi * 256 + threadIdx.x; i < N_INC; i += SCAT_STRIDE) {
            int e = ei[i], v = ni[i];
            if ((e & 7) == owner) {
                int p = atomicAdd(&cnt_e[e], 1);
                if (p < ECAP) staged_e[e * ECAP + p] = v;
                atomicAdd(&e_den[e], w[v]);
            }
            if ((v & 7) == owner) {
                int p = atomicAdd(&cnt_v[v], 1);
                if (p < VCAP) staged_v[v * VCAP + p] = e;
            }
        }
    } else {
        // ---- GEMM: T[v] = (H @ W1)[v] * w[v], one wave per 16x16 tile ----
        int wave = ((blockIdx.x - SCAT_BLOCKS) * 256 + threadIdx.x) >> 6;
        if (wave >= N_NODES / 16) return;        // wave-uniform guard
        int lane = threadIdx.x & 63;
        int m = lane & 15, q = lane >> 4;
        int row0 = wave * 16;
        const float* hp = H + (size_t)(row0 + m) * D_IN + q * 8;

        bf16x8 bf[8];
        const int4* bp = (const int4*)bfrag;
#pragma unroll
        for (int c = 0; c < 8; ++c) {
            int4 raw = bp[c * 64 + lane];
            bf[c] = *(bf16x8*)&raw;
        }
        f32x4 acc = {0.f, 0.f, 0.f, 0.f};
#pragma unroll
        for (int c = 0; c < 8; ++c) {
            float4 lo = *(const float4*)(hp + c * 32);
            float4 hi = *(const float4*)(hp + c * 32 + 4);
            bf16x8 af;
            af[0] = f2bf(lo.x); af[1] = f2bf(lo.y); af[2] = f2bf(lo.z); af[3] = f2bf(lo.w);
            af[4] = f2bf(hi.x); af[5] = f2bf(hi.y); af[6] = f2bf(hi.z); af[7] = f2bf(hi.w);
            acc = __builtin_amdgcn_mfma_f32_16x16x32_bf16(af, bf[c], acc, 0, 0, 0);
        }
        // C/D layout: col = lane&15, row = q*4 + reg; scale row by w[row]
#pragma unroll
        for (int r = 0; r < 4; ++r) {
            int row = row0 + q * 4 + r;
            T[(size_t)row * D_H + m] = acc[r] * w[row];
        }
    }
}

// ---------------- gatherA: node -> edge, one wave per edge ----------------------
// X rows are pre-scaled by w, so sum then divide by precomputed e_den.
__global__ __launch_bounds__(256) void gatherA_kernel(
    const int* __restrict__ cnt_e, const float* __restrict__ e_den,
    const int* __restrict__ staged_e,
    const float* __restrict__ X, float* __restrict__ e_feat) {
    int e = (blockIdx.x * 256 + threadIdx.x) >> 6;
    if (e >= N_EDGES) return;
    int lane = threadIdx.x & 63;
    int s = lane >> 4, j = lane & 15;
    int cnt = min(cnt_e[e], ECAP);
    const int* rp = staged_e + e * ECAP;
    float acc = 0.f;
    for (int k = s; k < cnt; k += 4)
        acc += X[(size_t)rp[k] * D_H + j];
    acc += __shfl_xor(acc, 16, 64);
    acc += __shfl_xor(acc, 32, 64);
    if (s == 0) e_feat[(size_t)e * D_H + j] = acc / fmaxf(e_den[e], 1e-6f);
}

// ---------------- gatherB layer 1: edge -> node, relu(mean+b1) * w --------------
__global__ __launch_bounds__(256) void gatherB1_kernel(
    const int* __restrict__ cnt_v, const int* __restrict__ staged_v,
    const float* __restrict__ e_feat, const float* __restrict__ w,
    const float* __restrict__ b1, float* __restrict__ out) {
    int t = blockIdx.x * 256 + threadIdx.x;
    int n = t >> 4;
    if (n >= N_NODES) return;
    int j = t & 15;
    int cnt = cnt_v[n];
    int use = min(cnt, VCAP);
    const int* rp = staged_v + n * VCAP;
    float acc = 0.f;
    for (int k = 0; k < use; ++k)
        acc += e_feat[(size_t)rp[k] * D_H + j];
    float inv = 1.f / fmaxf((float)cnt, 1.f);
    out[(size_t)n * D_H + j] = fmaxf(acc * inv + b1[j], 0.f) * w[n];
}

// ---------------- gatherB layer 2 + W2 matmul + log_softmax fused ---------------
// 256 threads = 16 nodes x 16 lanes.
__global__ __launch_bounds__(256) void gatherB2_final_kernel(
    const int* __restrict__ cnt_v, const int* __restrict__ staged_v,
    const float* __restrict__ e_feat,
    const float* __restrict__ W2, const float* __restrict__ b2,
    float* __restrict__ out) {
    __shared__ float sy[16 * 17];
    __shared__ float sW2[D_H * D_OUT];
    __shared__ float sb2[D_OUT];
    int t = threadIdx.x;
    for (int i = t; i < D_H * D_OUT; i += 256) sW2[i] = W2[i];
    if (t < D_OUT) sb2[t] = b2[t];
    int nl = t >> 4, j = t & 15;
    int n = blockIdx.x * 16 + nl;
    float y = 0.f;
    if (n < N_NODES) {
        int cnt = cnt_v[n];
        int use = min(cnt, VCAP);
        const int* rp = staged_v + n * VCAP;
        float acc = 0.f;
        for (int k = 0; k < use; ++k)
            acc += e_feat[(size_t)rp[k] * D_H + j];
        y = acc / fmaxf((float)cnt, 1.f);
    }
    sy[nl * 17 + j] = y;
    __syncthreads();
    if (n >= N_NODES) return;
    // z for c = j, j+16, (j+32 if j<8)
    float z0 = sb2[j], z1 = sb2[j + 16];
    float z2 = (j < 8) ? sb2[j + 32] : -1e30f;
#pragma unroll
    for (int jj = 0; jj < D_H; ++jj) {
        float yy = sy[nl * 17 + jj];
        z0 += yy * sW2[jj * D_OUT + j];
        z1 += yy * sW2[jj * D_OUT + j + 16];
        if (j < 8) z2 += yy * sW2[jj * D_OUT + j + 32];
    }
    float m = fmaxf(fmaxf(z0, z1), z2);
#pragma unroll
    for (int o = 1; o < 16; o <<= 1) m = fmaxf(m, __shfl_xor(m, o, 64));
    float se = __expf(z0 - m) + __expf(z1 - m) + ((j < 8) ? __expf(z2 - m) : 0.f);
#pragma unroll
    for (int o = 1; o < 16; o <<= 1) se += __shfl_xor(se, o, 64);
    float lse = m + __logf(se);
    float* o = out + (size_t)n * D_OUT;
    o[j] = z0 - lse;
    o[j + 16] = z1 - lse;
    if (j < 8) o[j + 32] = z2 - lse;
}

extern "C" void kernel_launch(void* const* d_in, const int* in_sizes, int n_in,
                              void* d_out, int out_size, void* d_ws, size_t ws_size,
                              hipStream_t stream) {
    const float* H  = (const float*)d_in[0];
    const float* w  = (const float*)d_in[1];
    const int*   ni = (const int*)d_in[2];
    const int*   ei = (const int*)d_in[3];
    const float* W1 = (const float*)d_in[4];
    const float* b1 = (const float*)d_in[5];
    const float* W2 = (const float*)d_in[6];
    const float* b2 = (const float*)d_in[7];
    float* out = (float*)d_out;

    // workspace layout (4-byte words)
    int*            ws_i     = (int*)d_ws;
    int*            cnt_e    = ws_i + 0;                      // 20,000
    int*            cnt_v    = ws_i + 20000;                  // 100,000
    float*          e_den    = (float*)(ws_i + 120000);       // 20,000
    unsigned short* bfrag    = (unsigned short*)(ws_i + 140000); // 4096 ush
    int*            staged_e = ws_i + 142048;                 // 20,000*96
    int*            staged_v = ws_i + 2062048;                // 100,000*32
    float*          T        = (float*)(ws_i + 5262048);      // 1,600,000
    float*          e_feat   = (float*)(ws_i + 6862048);      // 320,000
    float*          x1       = (float*)(ws_i + 7182048);      // 1,600,000
    // total 8,782,048 words = 35.1 MB

    init_kernel<<<128, 512, 0, stream>>>(W1, bfrag, cnt_e);

    scat_gemm_kernel<<<SCAT_BLOCKS + GEMM_BLOCKS, 256, 0, stream>>>(
        ni, ei, w, cnt_e, cnt_v, e_den, staged_e, staged_v, H, bfrag, T);

    const int gA_grid = (N_EDGES * 64 + 255) / 256;   // 5000
    const int gB_grid = (N_NODES * 16 + 255) / 256;   // 6250

    // layer 1
    gatherA_kernel<<<gA_grid, 256, 0, stream>>>(cnt_e, e_den, staged_e, T, e_feat);
    gatherB1_kernel<<<gB_grid, 256, 0, stream>>>(cnt_v, staged_v, e_feat, w, b1, x1);
    // layer 2 (+ final matmul + log_softmax fused)
    gatherA_kernel<<<gA_grid, 256, 0, stream>>>(cnt_e, e_den, staged_e, x1, e_feat);
    gatherB2_final_kernel<<<(N_NODES + 15) / 16, 256, 0, stream>>>(
        cnt_v, staged_v, e_feat, W2, b2, out);
}

// Round 4
// 249.580 us; speedup vs baseline: 2.5217x; 1.5513x over previous
//
#include <hip/hip_runtime.h>

#define N_NODES 100000
#define N_EDGES 20000
#define N_INC   800000
#define D_IN    256
#define D_H     16
#define D_OUT   40

// two-pass LDS radix (atomic-minimal list builder, proven in round 0), finer buckets:
// edge buckets: 32 edges, 625 buckets; cap 1600 recs (mean 1280, +8.9 sigma)
// node buckets: 256 nodes, 392 buckets; cap 2400 recs (mean 2048, +7.8 sigma)
#define EBS    32
#define NBE    625
#define ECAP   1600
#define VBS    256
#define NBV    392
#define VCAP   2400
#define TE     4096
#define EPART  196          // ceil(800000/4096)
#define TV     6144
#define NPART  131          // ceil(800000/6144)
#define GEMM_BLOCKS 782     // 6250 waves / 8 waves-per-512-block

typedef short bf16x8 __attribute__((ext_vector_type(8)));
typedef float f32x4  __attribute__((ext_vector_type(4)));

__device__ __forceinline__ unsigned short f2bf(float f) {
    unsigned u = __float_as_uint(f);
    unsigned r = u + 0x7FFF + ((u >> 16) & 1);   // round-to-nearest-even
    return (unsigned short)(r >> 16);
}

// ---------------- K0: pack W1 into MFMA B-frag layout; zero bucket counters ----
__global__ __launch_bounds__(512) void init_kernel(
    const float* __restrict__ W1, unsigned short* __restrict__ bfrag,
    int* __restrict__ cnts /* cnt_be(625) @0 ++ cnt_bv(392) @640 */) {
    int t = threadIdx.x;
    for (int i = t; i < 1032; i += 512) cnts[i] = 0;
    int c = t >> 6, l = t & 63;          // 512 threads = 8 chunks x 64 lanes
    int n = l & 15, q = l >> 4;
    unsigned short v[8];
#pragma unroll
    for (int j = 0; j < 8; ++j)
        v[j] = f2bf(W1[(c * 32 + q * 8 + j) * D_H + n]);
    *(int4*)(bfrag + (size_t)(c * 64 + l) * 8) = *(int4*)v;
}

// ---------------- K1: part-edge(196) | part-node(131) | GEMM(782) --------------
// edge rec: v(17) | (e&31)<<17 | (e>>5)<<22      node rec: e(15) | (v&255)<<15 | (v>>8)<<23
union SMemP {
    struct { int lrec[TE]; int lhist[NBE]; int lbase[NBE];
             int gbase[NBE]; int lcur[NBE]; int sc[512]; } pe;
    struct { int lrec[TV]; int lhist[NBV]; int lbase[NBV];
             int gbase[NBV]; int lcur[NBV]; int sc[512]; } pn;
};

__global__ __launch_bounds__(512) void part_gemm_kernel(
    const int* __restrict__ ni, const int* __restrict__ ei,
    const float* __restrict__ w,
    int* __restrict__ cnt_be, int* __restrict__ cnt_bv,
    int* __restrict__ staged_e, int* __restrict__ staged_v,
    const float* __restrict__ H, const unsigned short* __restrict__ bfrag,
    float* __restrict__ T) {
    __shared__ SMemP sm;
    int t = threadIdx.x;
    if (blockIdx.x < EPART) {
        int base = blockIdx.x * TE;
        for (int i = t; i < NBE; i += 512) sm.pe.lhist[i] = 0;
        __syncthreads();
#pragma unroll
        for (int r = 0; r < TE / 512; ++r) {
            int idx = base + r * 512 + t;
            if (idx < N_INC) atomicAdd(&sm.pe.lhist[ei[idx] >> 5], 1);
        }
        __syncthreads();
        // 625 bins, 2 per thread, 512-wide Hillis-Steele over pair sums
        int b0 = 2 * t, b1 = 2 * t + 1;
        int h0 = (b0 < NBE) ? sm.pe.lhist[b0] : 0;
        int h1 = (b1 < NBE) ? sm.pe.lhist[b1] : 0;
        int local = h0 + h1;
        sm.pe.sc[t] = local; __syncthreads();
        for (int o = 1; o < 512; o <<= 1) {
            int x = (t >= o) ? sm.pe.sc[t - o] : 0; __syncthreads();
            sm.pe.sc[t] += x; __syncthreads();
        }
        int ex = sm.pe.sc[t] - local;
        if (b0 < NBE) {
            sm.pe.lbase[b0] = ex; sm.pe.lcur[b0] = ex;
            sm.pe.gbase[b0] = h0 ? (b0 * ECAP + atomicAdd(&cnt_be[b0], h0)) : 0;
        }
        if (b1 < NBE) {
            int ex1 = ex + h0;
            sm.pe.lbase[b1] = ex1; sm.pe.lcur[b1] = ex1;
            sm.pe.gbase[b1] = h1 ? (b1 * ECAP + atomicAdd(&cnt_be[b1], h1)) : 0;
        }
        __syncthreads();
#pragma unroll
        for (int r = 0; r < TE / 512; ++r) {
            int idx = base + r * 512 + t;
            if (idx < N_INC) {
                int e = ei[idx], v = ni[idx];
                int key = e >> 5;
                int rec = v | ((e & 31) << 17) | (key << 22);
                int p = atomicAdd(&sm.pe.lcur[key], 1);
                sm.pe.lrec[p] = rec;
            }
        }
        __syncthreads();
        int total = min(TE, N_INC - base);
        for (int i = t; i < total; i += 512) {
            int rec = sm.pe.lrec[i];
            int bk = ((unsigned)rec) >> 22;
            int dst = sm.pe.gbase[bk] + (i - sm.pe.lbase[bk]);
            if (dst < (bk + 1) * ECAP) staged_e[dst] = rec;
        }
    } else if (blockIdx.x < EPART + NPART) {
        int base = (blockIdx.x - EPART) * TV;
        for (int i = t; i < NBV; i += 512) sm.pn.lhist[i] = 0;
        __syncthreads();
#pragma unroll
        for (int r = 0; r < TV / 512; ++r) {
            int idx = base + r * 512 + t;
            if (idx < N_INC) atomicAdd(&sm.pn.lhist[ni[idx] >> 8], 1);
        }
        __syncthreads();
        int h = (t < NBV) ? sm.pn.lhist[t] : 0;
        sm.pn.sc[t] = h; __syncthreads();
        for (int o = 1; o < 512; o <<= 1) {
            int x = (t >= o) ? sm.pn.sc[t - o] : 0; __syncthreads();
            sm.pn.sc[t] += x; __syncthreads();
        }
        if (t < NBV) {
            int ex = sm.pn.sc[t] - h;
            sm.pn.lbase[t] = ex; sm.pn.lcur[t] = ex;
            sm.pn.gbase[t] = h ? (t * VCAP + atomicAdd(&cnt_bv[t], h)) : 0;
        }
        __syncthreads();
#pragma unroll
        for (int r = 0; r < TV / 512; ++r) {
            int idx = base + r * 512 + t;
            if (idx < N_INC) {
                int e = ei[idx], v = ni[idx];
                int key = v >> 8;
                int rec = e | ((v & 255) << 15) | (key << 23);
                int p = atomicAdd(&sm.pn.lcur[key], 1);
                sm.pn.lrec[p] = rec;
            }
        }
        __syncthreads();
        int total = min(TV, N_INC - base);
        for (int i = t; i < total; i += 512) {
            int rec = sm.pn.lrec[i];
            int bk = ((unsigned)rec) >> 23;
            int dst = sm.pn.gbase[bk] + (i - sm.pn.lbase[bk]);
            if (dst < (bk + 1) * VCAP) staged_v[dst] = rec;
        }
    } else {
        // ---- GEMM: T[v] = (H @ W1)[v] * w[v], one wave per 16x16 tile ----
        int wave = ((blockIdx.x - EPART - NPART) * 512 + t) >> 6;
        if (wave >= N_NODES / 16) return;        // wave-uniform guard
        int lane = t & 63;
        int m = lane & 15, q = lane >> 4;
        int row0 = wave * 16;
        const float* hp = H + (size_t)(row0 + m) * D_IN + q * 8;
        bf16x8 bf[8];
        const int4* bp = (const int4*)bfrag;
#pragma unroll
        for (int c = 0; c < 8; ++c) {
            int4 raw = bp[c * 64 + lane];
            bf[c] = *(bf16x8*)&raw;
        }
        f32x4 acc = {0.f, 0.f, 0.f, 0.f};
#pragma unroll
        for (int c = 0; c < 8; ++c) {
            float4 lo = *(const float4*)(hp + c * 32);
            float4 hi = *(const float4*)(hp + c * 32 + 4);
            bf16x8 af;
            af[0] = f2bf(lo.x); af[1] = f2bf(lo.y); af[2] = f2bf(lo.z); af[3] = f2bf(lo.w);
            af[4] = f2bf(hi.x); af[5] = f2bf(hi.y); af[6] = f2bf(hi.z); af[7] = f2bf(hi.w);
            acc = __builtin_amdgcn_mfma_f32_16x16x32_bf16(af, bf[c], acc, 0, 0, 0);
        }
#pragma unroll
        for (int r = 0; r < 4; ++r) {
            int row = row0 + q * 4 + r;
            T[(size_t)row * D_H + m] = acc[r] * w[row];   // pre-scale by w
        }
    }
}

// ---------------- K2: per-bucket counting sort, edge side -> exact CSR ----------
__global__ __launch_bounds__(512) void mega2e_kernel(
    const int* __restrict__ cnt_be, int* __restrict__ staged_e,
    int2* __restrict__ off_e2) {
    __shared__ int lsort[ECAP];
    __shared__ int hist[EBS], cursor[EBS];
    int b = blockIdx.x, t = threadIdx.x;
    int beg = b * ECAP, cnt = min(cnt_be[b], ECAP);
    if (t < EBS) hist[t] = 0;
    __syncthreads();
    int rec[4], key[4], nr = 0;
#pragma unroll
    for (int r = 0; r < 4; ++r) {
        int k = r * 512 + t;
        if (k < cnt) {
            rec[nr] = staged_e[beg + k];
            key[nr] = (rec[nr] >> 17) & 31;
            atomicAdd(&hist[key[nr]], 1);
            ++nr;
        }
    }
    __syncthreads();
    if (t < EBS) {
        int hh = hist[t], s = hh;
#pragma unroll
        for (int o = 1; o < EBS; o <<= 1) {
            int x = __shfl_up(s, o, 64);
            if (t >= o) s += x;
        }
        int ex = s - hh;
        cursor[t] = ex;
        off_e2[b * EBS + t] = make_int2(beg + ex, beg + ex + hh);  // 625*32 = 20000 exact
    }
    __syncthreads();
    for (int r = 0; r < nr; ++r) {
        int p = atomicAdd(&cursor[key[r]], 1);
        lsort[p] = rec[r];
    }
    __syncthreads();
    for (int i = t; i < cnt; i += 512) staged_e[beg + i] = lsort[i];
}

// ---------------- K3: mega2-node(196) || gatherA layer-1 (2500) ----------------
// gatherA: wave per edge; 16 record-groups x 4 lanes, float4 j-quads. Computes
// e_den once (w gathers) and stores it for layer 2. X rows pre-scaled by w.
__global__ __launch_bounds__(512) void m2n_gA1_kernel(
    const int* __restrict__ cnt_bv, int* __restrict__ staged_v,
    int2* __restrict__ off_v2,
    const int2* __restrict__ off_e2, const int* __restrict__ staged_e,
    const float* __restrict__ T, const float* __restrict__ w,
    float* __restrict__ e_den, float* __restrict__ e_feat) {
    __shared__ int lsort[VCAP];
    __shared__ int hist[VBS], cursor[VBS], sc[512];
    int t = threadIdx.x;
    if (blockIdx.x < NBV) {
        int b = blockIdx.x;
        int beg = b * VCAP, cnt = min(cnt_bv[b], VCAP);
        for (int i = t; i < VBS; i += 512) hist[i] = 0;
        __syncthreads();
        int rec[5], key[5], nr = 0;
#pragma unroll
        for (int r = 0; r < 5; ++r) {
            int k = r * 512 + t;
            if (k < cnt) {
                rec[nr] = staged_v[beg + k];
                key[nr] = (rec[nr] >> 15) & 255;
                atomicAdd(&hist[key[nr]], 1);
                ++nr;
            }
        }
        __syncthreads();
        int hh = (t < VBS) ? hist[t] : 0;
        sc[t] = hh; __syncthreads();
        for (int o = 1; o < 512; o <<= 1) {
            int x = (t >= o) ? sc[t - o] : 0; __syncthreads();
            sc[t] += x; __syncthreads();
        }
        if (t < VBS) {
            int ex = sc[t] - hh;
            cursor[t] = ex;
            int n = b * VBS + t;
            if (n < N_NODES) off_v2[n] = make_int2(beg + ex, beg + ex + hh);
        }
        __syncthreads();
        for (int r = 0; r < nr; ++r) {
            int p = atomicAdd(&cursor[key[r]], 1);
            lsort[p] = rec[r];
        }
        __syncthreads();
        for (int i = t; i < cnt; i += 512) staged_v[beg + i] = lsort[i];
    } else {
        int e = ((blockIdx.x - NBV) * 512 + t) >> 6;
        if (e >= N_EDGES) return;            // wave-uniform
        int lane = t & 63;
        int g = lane >> 2, c = (lane & 3) << 2;
        int2 be = off_e2[e];
        f32x4 acc = {0.f, 0.f, 0.f, 0.f};
        float den = 0.f;
        for (int k = be.x + g; k < be.y; k += 16) {
            int rec = staged_e[k];
            int v = rec & 0x1FFFF;
            acc += *(const f32x4*)(T + (size_t)v * D_H + c);
            if ((lane & 3) == 0) den += w[v];
        }
#pragma unroll
        for (int s = 4; s <= 32; s <<= 1) {
            acc[0] += __shfl_xor(acc[0], s, 64);
            acc[1] += __shfl_xor(acc[1], s, 64);
            acc[2] += __shfl_xor(acc[2], s, 64);
            acc[3] += __shfl_xor(acc[3], s, 64);
            den    += __shfl_xor(den,    s, 64);
        }
        den = __shfl(den, 0, 64);
        if (lane == 0) e_den[e] = den;
        float inv = 1.f / fmaxf(den, 1e-6f);
        if (lane < 4) {
            f32x4 r = acc * inv;
            *(f32x4*)(e_feat + (size_t)e * D_H + c) = r;
        }
    }
}

// ---------------- K5: gatherA layer-2 (reuses e_den) ----------------------------
__global__ __launch_bounds__(512) void gatherA2_kernel(
    const int2* __restrict__ off_e2, const int* __restrict__ staged_e,
    const float* __restrict__ X, const float* __restrict__ e_den,
    float* __restrict__ e_feat) {
    int e = (blockIdx.x * 512 + threadIdx.x) >> 6;
    if (e >= N_EDGES) return;
    int lane = threadIdx.x & 63;
    int g = lane >> 2, c = (lane & 3) << 2;
    int2 be = off_e2[e];
    f32x4 acc = {0.f, 0.f, 0.f, 0.f};
    for (int k = be.x + g; k < be.y; k += 16) {
        int rec = staged_e[k];
        int v = rec & 0x1FFFF;
        acc += *(const f32x4*)(X + (size_t)v * D_H + c);
    }
#pragma unroll
    for (int s = 4; s <= 32; s <<= 1) {
        acc[0] += __shfl_xor(acc[0], s, 64);
        acc[1] += __shfl_xor(acc[1], s, 64);
        acc[2] += __shfl_xor(acc[2], s, 64);
        acc[3] += __shfl_xor(acc[3], s, 64);
    }
    if (lane < 4) {
        float inv = 1.f / fmaxf(e_den[e], 1e-6f);
        f32x4 r = acc * inv;
        *(f32x4*)(e_feat + (size_t)e * D_H + c) = r;
    }
}

// ---------------- K4: gatherB layer 1: 4 lanes/node, relu(mean+b1)*w ------------
__global__ __launch_bounds__(512) void gatherB1_kernel(
    const int2* __restrict__ off_v2, const int* __restrict__ staged_v,
    const float* __restrict__ e_feat, const float* __restrict__ w,
    const float* __restrict__ b1, float* __restrict__ out) {
    int t = blockIdx.x * 512 + threadIdx.x;
    int n = t >> 2;
    if (n >= N_NODES) return;
    int c = (t & 3) << 2;
    int2 be = off_v2[n];
    f32x4 acc = {0.f, 0.f, 0.f, 0.f};
    for (int k = be.x; k < be.y; ++k) {
        int e = staged_v[k] & 0x7FFF;
        acc += *(const f32x4*)(e_feat + (size_t)e * D_H + c);
    }
    float inv = 1.f / fmaxf((float)(be.y - be.x), 1.f);
    f32x4 bb = *(const f32x4*)(b1 + c);
    float wn = w[n];
    f32x4 r;
#pragma unroll
    for (int i = 0; i < 4; ++i) r[i] = fmaxf(acc[i] * inv + bb[i], 0.f) * wn;
    *(f32x4*)(out + (size_t)n * D_H + c) = r;
}

// ---------------- K6: gatherB layer 2 + W2 matmul + log_softmax -----------------
// 512 thr = 128 nodes x 4 lanes. Phase 1: mean -> sy. Phase 2: lane handles 10
// classes; softmax across the 4-lane group.
__global__ __launch_bounds__(512) void gatherB2_final_kernel(
    const int2* __restrict__ off_v2, const int* __restrict__ staged_v,
    const float* __restrict__ e_feat,
    const float* __restrict__ W2, const float* __restrict__ b2,
    float* __restrict__ out) {
    __shared__ float sy[128 * 20];
    __shared__ float sW2[D_H * D_OUT];
    __shared__ float sb2[D_OUT];
    int t = threadIdx.x;
    for (int i = t; i < D_H * D_OUT; i += 512) sW2[i] = W2[i];
    if (t < D_OUT) sb2[t] = b2[t];
    int nl = t >> 2, c = (t & 3) << 2;
    int n = blockIdx.x * 128 + nl;
    f32x4 y = {0.f, 0.f, 0.f, 0.f};
    if (n < N_NODES) {
        int2 be = off_v2[n];
        f32x4 acc = {0.f, 0.f, 0.f, 0.f};
        for (int k = be.x; k < be.y; ++k) {
            int e = staged_v[k] & 0x7FFF;
            acc += *(const f32x4*)(e_feat + (size_t)e * D_H + c);
        }
        float inv = 1.f / fmaxf((float)(be.y - be.x), 1.f);
        y = acc * inv;
    }
    *(f32x4*)(sy + nl * 20 + c) = y;
    __syncthreads();
    if (n >= N_NODES) return;
    int c0 = (t & 3) * 10;
    float z[10];
#pragma unroll
    for (int i = 0; i < 10; ++i) z[i] = sb2[c0 + i];
#pragma unroll
    for (int jj = 0; jj < D_H; ++jj) {
        float yy = sy[nl * 20 + jj];
#pragma unroll
        for (int i = 0; i < 10; ++i) z[i] += yy * sW2[jj * D_OUT + c0 + i];
    }
    float m = z[0];
#pragma unroll
    for (int i = 1; i < 10; ++i) m = fmaxf(m, z[i]);
    m = fmaxf(m, __shfl_xor(m, 1, 64));
    m = fmaxf(m, __shfl_xor(m, 2, 64));
    float se = 0.f;
#pragma unroll
    for (int i = 0; i < 10; ++i) se += __expf(z[i] - m);
    se += __shfl_xor(se, 1, 64);
    se += __shfl_xor(se, 2, 64);
    float lse = m + __logf(se);
    float* op = out + (size_t)n * D_OUT + c0;
#pragma unroll
    for (int i = 0; i < 10; ++i) op[i] = z[i] - lse;
}

extern "C" void kernel_launch(void* const* d_in, const int* in_sizes, int n_in,
                              void* d_out, int out_size, void* d_ws, size_t ws_size,
                              hipStream_t stream) {
    const float* H  = (const float*)d_in[0];
    const float* w  = (const float*)d_in[1];
    const int*   ni = (const int*)d_in[2];
    const int*   ei = (const int*)d_in[3];
    const float* W1 = (const float*)d_in[4];
    const float* b1 = (const float*)d_in[5];
    const float* W2 = (const float*)d_in[6];
    const float* b2 = (const float*)d_in[7];
    float* out = (float*)d_out;

    // workspace layout (4-byte words)
    int*            ws_i     = (int*)d_ws;
    int*            cnt_be   = ws_i + 0;                      // 625
    int*            cnt_bv   = ws_i + 640;                    // 392
    unsigned short* bfrag    = (unsigned short*)(ws_i + 1040);// 4096 ush = 2048 w
    int2*           off_e2   = (int2*)(ws_i + 3088);          // 20000 int2
    int2*           off_v2   = (int2*)(ws_i + 43088);         // 100000 int2
    int*            staged_e = ws_i + 243088;                 // 625*1600
    int*            staged_v = ws_i + 1243088;                // 392*2400
    float*          e_den    = (float*)(ws_i + 2183888);      // 20000
    float*          T        = (float*)(ws_i + 2203888);      // 1,600,000
    float*          e_feat   = (float*)(ws_i + 3803888);      // 320,000
    float*          x1       = (float*)(ws_i + 4123888);      // 1,600,000
    // total 5,723,888 words = 22.9 MB

    init_kernel<<<1, 512, 0, stream>>>(W1, bfrag, cnt_be);

    part_gemm_kernel<<<EPART + NPART + GEMM_BLOCKS, 512, 0, stream>>>(
        ni, ei, w, cnt_be, cnt_bv, staged_e, staged_v, H, bfrag, T);

    mega2e_kernel<<<NBE, 512, 0, stream>>>(cnt_be, staged_e, off_e2);

    // mega2-node || gatherA layer 1
    m2n_gA1_kernel<<<NBV + 2500, 512, 0, stream>>>(
        cnt_bv, staged_v, off_v2, off_e2, staged_e, T, w, e_den, e_feat);

    gatherB1_kernel<<<782, 512, 0, stream>>>(off_v2, staged_v, e_feat, w, b1, x1);

    gatherA2_kernel<<<2500, 512, 0, stream>>>(off_e2, staged_e, x1, e_den, e_feat);

    gatherB2_final_kernel<<<782, 512, 0, stream>>>(
        off_v2, staged_v, e_feat, W2, b2, out);
}

// Round 5
// 247.237 us; speedup vs baseline: 2.5456x; 1.0095x over previous
//
#include <hip/hip_runtime.h>

#define N_NODES 100000
#define N_EDGES 20000
#define N_INC   800000
#define D_IN    256
#define D_H     16
#define D_OUT   40

// two-pass LDS radix list builder; fine buckets:
// edge buckets: 32 edges, 625 buckets; cap 1600 recs (mean 1280, +8.9 sigma)
// node buckets: 256 nodes, 392 buckets; cap 2400 recs (mean 2048, +7.8 sigma)
#define EBS    32
#define NBE    625
#define ECAP   1600
#define VBS    256
#define NBV    392
#define VCAP   2400
#define TE     4096
#define EPART  196          // ceil(800000/4096)
#define TV     6144
#define NPART  131          // ceil(800000/6144)
#define GEMM_BLOCKS 782     // 6250 waves / 8 waves-per-512-block

typedef short bf16x8 __attribute__((ext_vector_type(8)));
typedef float f32x4  __attribute__((ext_vector_type(4)));

__device__ __forceinline__ unsigned short f2bf(float f) {
    unsigned u = __float_as_uint(f);
    unsigned r = u + 0x7FFF + ((u >> 16) & 1);   // round-to-nearest-even
    return (unsigned short)(r >> 16);
}

// block-wide exclusive scan over 512 threads: wave shfl-scan + 8-word combine.
// 1 barrier instead of 18. sc8 must be >= 8 ints; caller syncs before reuse.
__device__ __forceinline__ int block_exscan512(int local, int* sc8) {
    int t = threadIdx.x, lane = t & 63, wid = t >> 6;
    int s = local;
#pragma unroll
    for (int o = 1; o < 64; o <<= 1) {
        int x = __shfl_up(s, o, 64);
        if (lane >= o) s += x;
    }
    if (lane == 63) sc8[wid] = s;
    __syncthreads();
    int wbase = 0;
#pragma unroll
    for (int i = 0; i < 8; ++i) if (i < wid) wbase += sc8[i];
    return wbase + s - local;
}

// ---------------- K0: pack W1 into MFMA B-frag layout; zero bucket counters ----
__global__ __launch_bounds__(512) void init_kernel(
    const float* __restrict__ W1, unsigned short* __restrict__ bfrag,
    int* __restrict__ cnts /* cnt_be(625) @0 ++ cnt_bv(392) @640 */) {
    int t = threadIdx.x;
    for (int i = t; i < 1040; i += 512) cnts[i] = 0;
    int c = t >> 6, l = t & 63;          // 512 threads = 8 chunks x 64 lanes
    int n = l & 15, q = l >> 4;
    unsigned short v[8];
#pragma unroll
    for (int j = 0; j < 8; ++j)
        v[j] = f2bf(W1[(c * 32 + q * 8 + j) * D_H + n]);
    *(int4*)(bfrag + (size_t)(c * 64 + l) * 8) = *(int4*)v;
}

// ---------------- K1: GEMM(782) | part-edge(196) | part-node(131) --------------
// GEMM blocks first: HBM streaming starts immediately; part fills in behind.
// edge rec: v(17) | (e&31)<<17 | (e>>5)<<22   node rec: e(15) | (v&255)<<15 | (v>>8)<<23
union SMemP {
    struct { int lrec[TE]; int lhist[NBE]; int lbase[NBE];
             int gbase[NBE]; int lcur[NBE]; int sc[8]; } pe;
    struct { int lrec[TV]; int lhist[NBV]; int lbase[NBV];
             int gbase[NBV]; int lcur[NBV]; int sc[8]; } pn;
};

__global__ __launch_bounds__(512) void part_gemm_kernel(
    const int* __restrict__ ni, const int* __restrict__ ei,
    const float* __restrict__ w,
    int* __restrict__ cnt_be, int* __restrict__ cnt_bv,
    int* __restrict__ staged_e, int* __restrict__ staged_v,
    const float* __restrict__ H, const unsigned short* __restrict__ bfrag,
    float* __restrict__ T) {
    __shared__ SMemP sm;
    int t = threadIdx.x;
    if (blockIdx.x < GEMM_BLOCKS) {
        // ---- GEMM: T[v] = (H @ W1)[v] * w[v], one wave per 16x16 tile ----
        int wave = (blockIdx.x * 512 + t) >> 6;
        if (wave >= N_NODES / 16) return;        // wave-uniform guard
        int lane = t & 63;
        int m = lane & 15, q = lane >> 4;
        int row0 = wave * 16;
        const float* hp = H + (size_t)(row0 + m) * D_IN + q * 8;
        bf16x8 bf[8];
        const int4* bp = (const int4*)bfrag;
#pragma unroll
        for (int c = 0; c < 8; ++c) {
            int4 raw = bp[c * 64 + lane];
            bf[c] = *(bf16x8*)&raw;
        }
        f32x4 acc = {0.f, 0.f, 0.f, 0.f};
#pragma unroll
        for (int c = 0; c < 8; ++c) {
            float4 lo = *(const float4*)(hp + c * 32);
            float4 hi = *(const float4*)(hp + c * 32 + 4);
            bf16x8 af;
            af[0] = f2bf(lo.x); af[1] = f2bf(lo.y); af[2] = f2bf(lo.z); af[3] = f2bf(lo.w);
            af[4] = f2bf(hi.x); af[5] = f2bf(hi.y); af[6] = f2bf(hi.z); af[7] = f2bf(hi.w);
            acc = __builtin_amdgcn_mfma_f32_16x16x32_bf16(af, bf[c], acc, 0, 0, 0);
        }
        // C/D layout: col = lane&15, row = q*4 + reg; pre-scale row by w
#pragma unroll
        for (int r = 0; r < 4; ++r) {
            int row = row0 + q * 4 + r;
            T[(size_t)row * D_H + m] = acc[r] * w[row];
        }
    } else if (blockIdx.x < GEMM_BLOCKS + EPART) {
        int base = (blockIdx.x - GEMM_BLOCKS) * TE;
        for (int i = t; i < NBE; i += 512) sm.pe.lhist[i] = 0;
        __syncthreads();
#pragma unroll
        for (int r = 0; r < TE / 512; ++r) {
            int idx = base + r * 512 + t;
            if (idx < N_INC) atomicAdd(&sm.pe.lhist[ei[idx] >> 5], 1);
        }
        __syncthreads();
        // 625 bins, 2 per thread
        int b0 = 2 * t, b1 = 2 * t + 1;
        int h0 = (b0 < NBE) ? sm.pe.lhist[b0] : 0;
        int h1 = (b1 < NBE) ? sm.pe.lhist[b1] : 0;
        int ex = block_exscan512(h0 + h1, sm.pe.sc);
        if (b0 < NBE) {
            sm.pe.lbase[b0] = ex; sm.pe.lcur[b0] = ex;
            sm.pe.gbase[b0] = h0 ? (b0 * ECAP + atomicAdd(&cnt_be[b0], h0)) : 0;
        }
        if (b1 < NBE) {
            int ex1 = ex + h0;
            sm.pe.lbase[b1] = ex1; sm.pe.lcur[b1] = ex1;
            sm.pe.gbase[b1] = h1 ? (b1 * ECAP + atomicAdd(&cnt_be[b1], h1)) : 0;
        }
        __syncthreads();
#pragma unroll
        for (int r = 0; r < TE / 512; ++r) {
            int idx = base + r * 512 + t;
            if (idx < N_INC) {
                int e = ei[idx], v = ni[idx];
                int key = e >> 5;
                int rec = v | ((e & 31) << 17) | (key << 22);
                int p = atomicAdd(&sm.pe.lcur[key], 1);
                sm.pe.lrec[p] = rec;
            }
        }
        __syncthreads();
        int total = min(TE, N_INC - base);
        for (int i = t; i < total; i += 512) {
            int rec = sm.pe.lrec[i];
            int bk = ((unsigned)rec) >> 22;
            int dst = sm.pe.gbase[bk] + (i - sm.pe.lbase[bk]);
            if (dst < (bk + 1) * ECAP) staged_e[dst] = rec;
        }
    } else {
        int base = (blockIdx.x - GEMM_BLOCKS - EPART) * TV;
        for (int i = t; i < NBV; i += 512) sm.pn.lhist[i] = 0;
        __syncthreads();
#pragma unroll
        for (int r = 0; r < TV / 512; ++r) {
            int idx = base + r * 512 + t;
            if (idx < N_INC) atomicAdd(&sm.pn.lhist[ni[idx] >> 8], 1);
        }
        __syncthreads();
        int h = (t < NBV) ? sm.pn.lhist[t] : 0;
        int ex = block_exscan512(h, sm.pn.sc);
        if (t < NBV) {
            sm.pn.lbase[t] = ex; sm.pn.lcur[t] = ex;
            sm.pn.gbase[t] = h ? (t * VCAP + atomicAdd(&cnt_bv[t], h)) : 0;
        }
        __syncthreads();
#pragma unroll
        for (int r = 0; r < TV / 512; ++r) {
            int idx = base + r * 512 + t;
            if (idx < N_INC) {
                int e = ei[idx], v = ni[idx];
                int key = v >> 8;
                int rec = e | ((v & 255) << 15) | (key << 23);
                int p = atomicAdd(&sm.pn.lcur[key], 1);
                sm.pn.lrec[p] = rec;
            }
        }
        __syncthreads();
        int total = min(TV, N_INC - base);
        for (int i = t; i < total; i += 512) {
            int rec = sm.pn.lrec[i];
            int bk = ((unsigned)rec) >> 23;
            int dst = sm.pn.gbase[bk] + (i - sm.pn.lbase[bk]);
            if (dst < (bk + 1) * VCAP) staged_v[dst] = rec;
        }
    }
}

// ---------------- K2: edge sort + fused gatherA layer-1 (625) | node sort (196) -
// Edge blocks: counting-sort bucket in LDS, write CSR + sorted recs back, then
// immediately aggregate e_feat from LDS records (T rows pre-scaled by w).
// Node blocks: counting-sort node buckets -> off_v2 + sorted staged_v.
union SMemS {
    struct { int lsort[ECAP]; int hist[EBS]; int cursor[EBS]; int lbeg[EBS]; } e;
    struct { int lsort[VCAP]; int hist[VBS]; int cursor[VBS]; int sc[8]; } v;
};

__global__ __launch_bounds__(512) void sortE_gA1_sortN_kernel(
    const int* __restrict__ cnt_be, int* __restrict__ staged_e,
    int2* __restrict__ off_e2,
    const int* __restrict__ cnt_bv, int* __restrict__ staged_v,
    int2* __restrict__ off_v2,
    const float* __restrict__ T, const float* __restrict__ w,
    float* __restrict__ e_den, float* __restrict__ e_feat) {
    __shared__ SMemS sm;
    int t = threadIdx.x;
    if (blockIdx.x < NBE) {
        int b = blockIdx.x;
        int beg = b * ECAP, cnt = min(cnt_be[b], ECAP);
        if (t < EBS) sm.e.hist[t] = 0;
        __syncthreads();
        int rec[4], key[4], nr = 0;
#pragma unroll
        for (int r = 0; r < 4; ++r) {
            int k = r * 512 + t;
            if (k < cnt) {
                rec[nr] = staged_e[beg + k];
                key[nr] = (rec[nr] >> 17) & 31;
                atomicAdd(&sm.e.hist[key[nr]], 1);
                ++nr;
            }
        }
        __syncthreads();
        if (t < EBS) {
            int hh = sm.e.hist[t], s = hh;
#pragma unroll
            for (int o = 1; o < EBS; o <<= 1) {
                int x = __shfl_up(s, o, 64);
                if (t >= o) s += x;
            }
            int ex = s - hh;
            sm.e.cursor[t] = ex; sm.e.lbeg[t] = ex;
            off_e2[b * EBS + t] = make_int2(beg + ex, beg + ex + hh);
        }
        __syncthreads();
        for (int r = 0; r < nr; ++r) {
            int p = atomicAdd(&sm.e.cursor[key[r]], 1);
            sm.e.lsort[p] = rec[r];
        }
        __syncthreads();
        // writeback sorted records for gatherA layer-2
        for (int i = t; i < cnt; i += 512) staged_e[beg + i] = sm.e.lsort[i];
        // fused gatherA layer-1: 32 edges x 16 lanes, records from LDS
        int el = t >> 4, j = t & 15;
        int lo = sm.e.lbeg[el], hi = lo + sm.e.hist[el];
        float acc = 0.f;
        int k = lo;
        for (; k + 4 <= hi; k += 4) {           // 4-deep MLP
            int r0 = sm.e.lsort[k]     & 0x1FFFF;
            int r1 = sm.e.lsort[k + 1] & 0x1FFFF;
            int r2 = sm.e.lsort[k + 2] & 0x1FFFF;
            int r3 = sm.e.lsort[k + 3] & 0x1FFFF;
            float t0 = T[(size_t)r0 * D_H + j];
            float t1 = T[(size_t)r1 * D_H + j];
            float t2 = T[(size_t)r2 * D_H + j];
            float t3 = T[(size_t)r3 * D_H + j];
            acc += t0; acc += t1; acc += t2; acc += t3;
        }
        for (; k < hi; ++k) acc += T[(size_t)(sm.e.lsort[k] & 0x1FFFF) * D_H + j];
        // denominator: lanes split the w-gather, xor-reduce within 16-cluster
        float den = 0.f;
        for (int k2 = lo + j; k2 < hi; k2 += 16) den += w[sm.e.lsort[k2] & 0x1FFFF];
#pragma unroll
        for (int o = 1; o < 16; o <<= 1) den += __shfl_xor(den, o, 64);
        int e = b * EBS + el;                    // 625*32 == 20000 exactly
        e_feat[(size_t)e * D_H + j] = acc / fmaxf(den, 1e-6f);
        if (j == 0) e_den[e] = den;
    } else {
        int b = blockIdx.x - NBE;
        int beg = b * VCAP, cnt = min(cnt_bv[b], VCAP);
        for (int i = t; i < VBS; i += 512) sm.v.hist[i] = 0;
        __syncthreads();
        int rec[5], key[5], nr = 0;
#pragma unroll
        for (int r = 0; r < 5; ++r) {
            int k = r * 512 + t;
            if (k < cnt) {
                rec[nr] = staged_v[beg + k];
                key[nr] = (rec[nr] >> 15) & 255;
                atomicAdd(&sm.v.hist[key[nr]], 1);
                ++nr;
            }
        }
        __syncthreads();
        int hh = (t < VBS) ? sm.v.hist[t] : 0;
        int ex = block_exscan512(hh, sm.v.sc);
        if (t < VBS) {
            sm.v.cursor[t] = ex;
            int n = b * VBS + t;
            if (n < N_NODES) off_v2[n] = make_int2(beg + ex, beg + ex + hh);
        }
        __syncthreads();
        for (int r = 0; r < nr; ++r) {
            int p = atomicAdd(&sm.v.cursor[key[r]], 1);
            sm.v.lsort[p] = rec[r];
        }
        __syncthreads();
        for (int i = t; i < cnt; i += 512) staged_v[beg + i] = sm.v.lsort[i];
    }
}

// ---------------- K3: gatherB layer 1: 4 lanes/node, relu(mean+b1)*w ------------
__global__ __launch_bounds__(512) void gatherB1_kernel(
    const int2* __restrict__ off_v2, const int* __restrict__ staged_v,
    const float* __restrict__ e_feat, const float* __restrict__ w,
    const float* __restrict__ b1, float* __restrict__ out) {
    int t = blockIdx.x * 512 + threadIdx.x;
    int n = t >> 2;
    if (n >= N_NODES) return;
    int c = (t & 3) << 2;
    int2 be = off_v2[n];
    f32x4 acc = {0.f, 0.f, 0.f, 0.f};
    for (int k = be.x; k < be.y; ++k) {
        int e = staged_v[k] & 0x7FFF;
        acc += *(const f32x4*)(e_feat + (size_t)e * D_H + c);
    }
    float inv = 1.f / fmaxf((float)(be.y - be.x), 1.f);
    f32x4 bb = *(const f32x4*)(b1 + c);
    float wn = w[n];
    f32x4 r;
#pragma unroll
    for (int i = 0; i < 4; ++i) r[i] = fmaxf(acc[i] * inv + bb[i], 0.f) * wn;
    *(f32x4*)(out + (size_t)n * D_H + c) = r;
}

// ---------------- K4: gatherA layer-2 (reuses e_den, sorted staged_e) -----------
__global__ __launch_bounds__(512) void gatherA2_kernel(
    const int2* __restrict__ off_e2, const int* __restrict__ staged_e,
    const float* __restrict__ X, const float* __restrict__ e_den,
    float* __restrict__ e_feat) {
    int e = (blockIdx.x * 512 + threadIdx.x) >> 6;
    if (e >= N_EDGES) return;
    int lane = threadIdx.x & 63;
    int g = lane >> 2, c = (lane & 3) << 2;
    int2 be = off_e2[e];
    f32x4 acc = {0.f, 0.f, 0.f, 0.f};
    for (int k = be.x + g; k < be.y; k += 16) {
        int rec = staged_e[k];
        int v = rec & 0x1FFFF;
        acc += *(const f32x4*)(X + (size_t)v * D_H + c);
    }
#pragma unroll
    for (int s = 4; s <= 32; s <<= 1) {
        acc[0] += __shfl_xor(acc[0], s, 64);
        acc[1] += __shfl_xor(acc[1], s, 64);
        acc[2] += __shfl_xor(acc[2], s, 64);
        acc[3] += __shfl_xor(acc[3], s, 64);
    }
    if (lane < 4) {
        float inv = 1.f / fmaxf(e_den[e], 1e-6f);
        f32x4 r = acc * inv;
        *(f32x4*)(e_feat + (size_t)e * D_H + c) = r;
    }
}

// ---------------- K5: gatherB layer 2 + W2 matmul + log_softmax -----------------
// 512 thr = 128 nodes x 4 lanes. Phase 1: mean -> sy. Phase 2: lane handles 10
// classes; softmax across the 4-lane group.
__global__ __launch_bounds__(512) void gatherB2_final_kernel(
    const int2* __restrict__ off_v2, const int* __restrict__ staged_v,
    const float* __restrict__ e_feat,
    const float* __restrict__ W2, const float* __restrict__ b2,
    float* __restrict__ out) {
    __shared__ float sy[128 * 20];
    __shared__ float sW2[D_H * D_OUT];
    __shared__ float sb2[D_OUT];
    int t = threadIdx.x;
    for (int i = t; i < D_H * D_OUT; i += 512) sW2[i] = W2[i];
    if (t < D_OUT) sb2[t] = b2[t];
    int nl = t >> 2, c = (t & 3) << 2;
    int n = blockIdx.x * 128 + nl;
    f32x4 y = {0.f, 0.f, 0.f, 0.f};
    if (n < N_NODES) {
        int2 be = off_v2[n];
        f32x4 acc = {0.f, 0.f, 0.f, 0.f};
        for (int k = be.x; k < be.y; ++k) {
            int e = staged_v[k] & 0x7FFF;
            acc += *(const f32x4*)(e_feat + (size_t)e * D_H + c);
        }
        float inv = 1.f / fmaxf((float)(be.y - be.x), 1.f);
        y = acc * inv;
    }
    *(f32x4*)(sy + nl * 20 + c) = y;
    __syncthreads();
    if (n >= N_NODES) return;
    int c0 = (t & 3) * 10;
    float z[10];
#pragma unroll
    for (int i = 0; i < 10; ++i) z[i] = sb2[c0 + i];
#pragma unroll
    for (int jj = 0; jj < D_H; ++jj) {
        float yy = sy[nl * 20 + jj];
#pragma unroll
        for (int i = 0; i < 10; ++i) z[i] += yy * sW2[jj * D_OUT + c0 + i];
    }
    float m = z[0];
#pragma unroll
    for (int i = 1; i < 10; ++i) m = fmaxf(m, z[i]);
    m = fmaxf(m, __shfl_xor(m, 1, 64));
    m = fmaxf(m, __shfl_xor(m, 2, 64));
    float se = 0.f;
#pragma unroll
    for (int i = 0; i < 10; ++i) se += __expf(z[i] - m);
    se += __shfl_xor(se, 1, 64);
    se += __shfl_xor(se, 2, 64);
    float lse = m + __logf(se);
    float* op = out + (size_t)n * D_OUT + c0;
#pragma unroll
    for (int i = 0; i < 10; ++i) op[i] = z[i] - lse;
}

extern "C" void kernel_launch(void* const* d_in, const int* in_sizes, int n_in,
                              void* d_out, int out_size, void* d_ws, size_t ws_size,
                              hipStream_t stream) {
    const float* H  = (const float*)d_in[0];
    const float* w  = (const float*)d_in[1];
    const int*   ni = (const int*)d_in[2];
    const int*   ei = (const int*)d_in[3];
    const float* W1 = (const float*)d_in[4];
    const float* b1 = (const float*)d_in[5];
    const float* W2 = (const float*)d_in[6];
    const float* b2 = (const float*)d_in[7];
    float* out = (float*)d_out;

    // workspace layout (4-byte words)
    int*            ws_i     = (int*)d_ws;
    int*            cnt_be   = ws_i + 0;                      // 625
    int*            cnt_bv   = ws_i + 640;                    // 392
    unsigned short* bfrag    = (unsigned short*)(ws_i + 1040);// 4096 ush = 2048 w
    int2*           off_e2   = (int2*)(ws_i + 3088);          // 20000 int2
    int2*           off_v2   = (int2*)(ws_i + 43088);         // 100000 int2
    int*            staged_e = ws_i + 243088;                 // 625*1600
    int*            staged_v = ws_i + 1243088;                // 392*2400
    float*          e_den    = (float*)(ws_i + 2183888);      // 20000
    float*          T        = (float*)(ws_i + 2203888);      // 1,600,000
    float*          e_feat   = (float*)(ws_i + 3803888);      // 320,000
    float*          x1       = (float*)(ws_i + 4123888);      // 1,600,000
    // total 5,723,888 words = 22.9 MB

    init_kernel<<<1, 512, 0, stream>>>(W1, bfrag, cnt_be);

    part_gemm_kernel<<<GEMM_BLOCKS + EPART + NPART, 512, 0, stream>>>(
        ni, ei, w, cnt_be, cnt_bv, staged_e, staged_v, H, bfrag, T);

    // edge sort + fused layer-1 edge aggregation || node sort
    sortE_gA1_sortN_kernel<<<NBE + NBV, 512, 0, stream>>>(
        cnt_be, staged_e, off_e2, cnt_bv, staged_v, off_v2, T, w, e_den, e_feat);

    gatherB1_kernel<<<782, 512, 0, stream>>>(off_v2, staged_v, e_feat, w, b1, x1);

    gatherA2_kernel<<<2500, 512, 0, stream>>>(off_e2, staged_e, x1, e_den, e_feat);

    gatherB2_final_kernel<<<782, 512, 0, stream>>>(
        off_v2, staged_v, e_feat, W2, b2, out);
}

// Round 6
// 242.412 us; speedup vs baseline: 2.5963x; 1.0199x over previous
//
#include <hip/hip_runtime.h>

#define N_NODES 100000
#define N_EDGES 20000
#define N_INC   800000
#define D_IN    256
#define D_H     16
#define D_OUT   40

// two-pass LDS radix list builder; fine buckets:
// edge buckets: 32 edges, 625 buckets; cap 1600 recs (mean 1280, +8.9 sigma)
// node buckets: 256 nodes, 392 buckets; cap 2400 recs (mean 2048, +7.8 sigma)
#define EBS    32
#define NBE    625
#define ECAP   1600
#define VBS    256
#define NBV    392
#define VCAP   2400
#define TE     4096
#define EPART  196          // ceil(800000/4096)
#define TV     6144
#define NPART  131          // ceil(800000/6144)
#define PTOT   327          // EPART + NPART
#define GEMM_BLOCKS 782     // 6250 waves / 8 waves-per-512-block
// K1 role interleave: every 10 blocks = 3 part + 7 gemm, so each CU's co-resident
// set holds both roles from t=0 (round-5 lesson: contiguous role ranges serialize
// the two phases through the FIFO dispatcher).
#define GRID_K1 1120        // 112 groups of 10: 336 part slots (>=327), 784 gemm (>=782)

typedef short bf16x8 __attribute__((ext_vector_type(8)));
typedef float f32x4  __attribute__((ext_vector_type(4)));

__device__ __forceinline__ unsigned short f2bf(float f) {
    unsigned u = __float_as_uint(f);
    unsigned r = u + 0x7FFF + ((u >> 16) & 1);   // round-to-nearest-even
    return (unsigned short)(r >> 16);
}

// block-wide exclusive scan over 512 threads: wave shfl-scan + 8-word combine.
__device__ __forceinline__ int block_exscan512(int local, int* sc8) {
    int t = threadIdx.x, lane = t & 63, wid = t >> 6;
    int s = local;
#pragma unroll
    for (int o = 1; o < 64; o <<= 1) {
        int x = __shfl_up(s, o, 64);
        if (lane >= o) s += x;
    }
    if (lane == 63) sc8[wid] = s;
    __syncthreads();
    int wbase = 0;
#pragma unroll
    for (int i = 0; i < 8; ++i) if (i < wid) wbase += sc8[i];
    return wbase + s - local;
}

// ---------------- K0: pack W1 into MFMA B-frag layout; zero bucket counters ----
__global__ __launch_bounds__(512) void init_kernel(
    const float* __restrict__ W1, unsigned short* __restrict__ bfrag,
    int* __restrict__ cnts /* cnt_be(625) @0 ++ cnt_bv(392) @640 */) {
    int t = threadIdx.x;
    for (int i = t; i < 1040; i += 512) cnts[i] = 0;
    int c = t >> 6, l = t & 63;          // 512 threads = 8 chunks x 64 lanes
    int n = l & 15, q = l >> 4;
    unsigned short v[8];
#pragma unroll
    for (int j = 0; j < 8; ++j)
        v[j] = f2bf(W1[(c * 32 + q * 8 + j) * D_H + n]);
    *(int4*)(bfrag + (size_t)(c * 64 + l) * 8) = *(int4*)v;
}

// ---------------- K1: interleaved part-edge | part-node | GEMM -----------------
// single-pass part: incidences read ONCE into registers; hist+scatter from regs.
// edge rec: v(17) | (e&31)<<17 | (e>>5)<<22   node rec: e(15) | (v&255)<<15 | (v>>8)<<23
union SMemP {
    struct { int lrec[TE]; int lhist[NBE]; int lbase[NBE];
             int gbase[NBE]; int lcur[NBE]; int sc[8]; } pe;
    struct { int lrec[TV]; int lhist[NBV]; int lbase[NBV];
             int gbase[NBV]; int lcur[NBV]; int sc[8]; } pn;
};

__global__ __launch_bounds__(512) void part_gemm_kernel(
    const int* __restrict__ ni, const int* __restrict__ ei,
    const float* __restrict__ w,
    int* __restrict__ cnt_be, int* __restrict__ cnt_bv,
    int* __restrict__ staged_e, int* __restrict__ staged_v,
    const float* __restrict__ H, const unsigned short* __restrict__ bfrag,
    float* __restrict__ T) {
    __shared__ SMemP sm;
    int t = threadIdx.x;
    int m10 = blockIdx.x % 10, g10 = blockIdx.x / 10;
    bool is_part = (m10 < 3);
    int pj = g10 * 3 + m10;              // part job id (if is_part)
    int gj = g10 * 7 + (m10 - 3);        // gemm job id (if !is_part)
    if (is_part && pj >= PTOT) return;
    if (!is_part && gj >= GEMM_BLOCKS) return;

    if (!is_part) {
        // ---- GEMM: T[v] = (H @ W1)[v] * w[v], one wave per 16x16 tile ----
        int wave = (gj * 512 + t) >> 6;
        if (wave >= N_NODES / 16) return;        // wave-uniform guard
        int lane = t & 63;
        int m = lane & 15, q = lane >> 4;
        int row0 = wave * 16;
        const float* hp = H + (size_t)(row0 + m) * D_IN + q * 8;
        bf16x8 bf[8];
        const int4* bp = (const int4*)bfrag;
#pragma unroll
        for (int c = 0; c < 8; ++c) {
            int4 raw = bp[c * 64 + lane];
            bf[c] = *(bf16x8*)&raw;
        }
        f32x4 acc = {0.f, 0.f, 0.f, 0.f};
#pragma unroll
        for (int c = 0; c < 8; ++c) {
            float4 lo = *(const float4*)(hp + c * 32);
            float4 hi = *(const float4*)(hp + c * 32 + 4);
            bf16x8 af;
            af[0] = f2bf(lo.x); af[1] = f2bf(lo.y); af[2] = f2bf(lo.z); af[3] = f2bf(lo.w);
            af[4] = f2bf(hi.x); af[5] = f2bf(hi.y); af[6] = f2bf(hi.z); af[7] = f2bf(hi.w);
            acc = __builtin_amdgcn_mfma_f32_16x16x32_bf16(af, bf[c], acc, 0, 0, 0);
        }
        // C/D layout: col = lane&15, row = q*4 + reg; pre-scale row by w
#pragma unroll
        for (int r = 0; r < 4; ++r) {
            int row = row0 + q * 4 + r;
            T[(size_t)row * D_H + m] = acc[r] * w[row];
        }
    } else if (pj < EPART) {
        int base = pj * TE;
        int rec[TE / 512];
        // single pass: load ei+ni once, build recs in regs, histogram
        for (int i = t; i < NBE; i += 512) sm.pe.lhist[i] = 0;
        __syncthreads();
#pragma unroll
        for (int r = 0; r < TE / 512; ++r) {
            int idx = base + r * 512 + t;
            rec[r] = -1;
            if (idx < N_INC) {
                int e = ei[idx], v = ni[idx];
                int key = e >> 5;
                rec[r] = v | ((e & 31) << 17) | (key << 22);
                atomicAdd(&sm.pe.lhist[key], 1);
            }
        }
        __syncthreads();
        // 625 bins, 2 per thread
        int b0 = 2 * t, b1 = 2 * t + 1;
        int h0 = (b0 < NBE) ? sm.pe.lhist[b0] : 0;
        int h1 = (b1 < NBE) ? sm.pe.lhist[b1] : 0;
        int ex = block_exscan512(h0 + h1, sm.pe.sc);
        if (b0 < NBE) {
            sm.pe.lbase[b0] = ex; sm.pe.lcur[b0] = ex;
            sm.pe.gbase[b0] = h0 ? (b0 * ECAP + atomicAdd(&cnt_be[b0], h0)) : 0;
        }
        if (b1 < NBE) {
            int ex1 = ex + h0;
            sm.pe.lbase[b1] = ex1; sm.pe.lcur[b1] = ex1;
            sm.pe.gbase[b1] = h1 ? (b1 * ECAP + atomicAdd(&cnt_be[b1], h1)) : 0;
        }
        __syncthreads();
#pragma unroll
        for (int r = 0; r < TE / 512; ++r) {
            if (rec[r] != -1) {
                int key = ((unsigned)rec[r]) >> 22;
                int p = atomicAdd(&sm.pe.lcur[key], 1);
                sm.pe.lrec[p] = rec[r];
            }
        }
        __syncthreads();
        int total = min(TE, N_INC - base);
        for (int i = t; i < total; i += 512) {
            int rr = sm.pe.lrec[i];
            int bk = ((unsigned)rr) >> 22;
            int dst = sm.pe.gbase[bk] + (i - sm.pe.lbase[bk]);
            if (dst < (bk + 1) * ECAP) staged_e[dst] = rr;
        }
    } else {
        int base = (pj - EPART) * TV;
        int rec[TV / 512];
        for (int i = t; i < NBV; i += 512) sm.pn.lhist[i] = 0;
        __syncthreads();
#pragma unroll
        for (int r = 0; r < TV / 512; ++r) {
            int idx = base + r * 512 + t;
            rec[r] = -1;
            if (idx < N_INC) {
                int e = ei[idx], v = ni[idx];
                int key = v >> 8;
                rec[r] = e | ((v & 255) << 15) | (key << 23);
                atomicAdd(&sm.pn.lhist[key], 1);
            }
        }
        __syncthreads();
        int h = (t < NBV) ? sm.pn.lhist[t] : 0;
        int ex = block_exscan512(h, sm.pn.sc);
        if (t < NBV) {
            sm.pn.lbase[t] = ex; sm.pn.lcur[t] = ex;
            sm.pn.gbase[t] = h ? (t * VCAP + atomicAdd(&cnt_bv[t], h)) : 0;
        }
        __syncthreads();
#pragma unroll
        for (int r = 0; r < TV / 512; ++r) {
            if (rec[r] != -1) {
                int key = ((unsigned)rec[r]) >> 23;
                int p = atomicAdd(&sm.pn.lcur[key], 1);
                sm.pn.lrec[p] = rec[r];
            }
        }
        __syncthreads();
        int total = min(TV, N_INC - base);
        for (int i = t; i < total; i += 512) {
            int rr = sm.pn.lrec[i];
            int bk = ((unsigned)rr) >> 23;
            int dst = sm.pn.gbase[bk] + (i - sm.pn.lbase[bk]);
            if (dst < (bk + 1) * VCAP) staged_v[dst] = rr;
        }
    }
}

// ---------------- K2: edge sort + fused gatherA layer-1 (625) | node sort (196) -
union SMemS {
    struct { int lsort[ECAP]; int hist[EBS]; int cursor[EBS]; int lbeg[EBS]; } e;
    struct { int lsort[VCAP]; int hist[VBS]; int cursor[VBS]; int sc[8]; } v;
};

__global__ __launch_bounds__(512) void sortE_gA1_sortN_kernel(
    const int* __restrict__ cnt_be, int* __restrict__ staged_e,
    int2* __restrict__ off_e2,
    const int* __restrict__ cnt_bv, int* __restrict__ staged_v,
    int2* __restrict__ off_v2,
    const float* __restrict__ T, const float* __restrict__ w,
    float* __restrict__ e_den, float* __restrict__ e_feat) {
    __shared__ SMemS sm;
    int t = threadIdx.x;
    if (blockIdx.x < NBE) {
        int b = blockIdx.x;
        int beg = b * ECAP, cnt = min(cnt_be[b], ECAP);
        if (t < EBS) sm.e.hist[t] = 0;
        __syncthreads();
        int rec[4], key[4], nr = 0;
#pragma unroll
        for (int r = 0; r < 4; ++r) {
            int k = r * 512 + t;
            if (k < cnt) {
                rec[nr] = staged_e[beg + k];
                key[nr] = (rec[nr] >> 17) & 31;
                atomicAdd(&sm.e.hist[key[nr]], 1);
                ++nr;
            }
        }
        __syncthreads();
        if (t < EBS) {
            int hh = sm.e.hist[t], s = hh;
#pragma unroll
            for (int o = 1; o < EBS; o <<= 1) {
                int x = __shfl_up(s, o, 64);
                if (t >= o) s += x;
            }
            int ex = s - hh;
            sm.e.cursor[t] = ex; sm.e.lbeg[t] = ex;
            off_e2[b * EBS + t] = make_int2(beg + ex, beg + ex + hh);
        }
        __syncthreads();
        for (int r = 0; r < nr; ++r) {
            int p = atomicAdd(&sm.e.cursor[key[r]], 1);
            sm.e.lsort[p] = rec[r];
        }
        __syncthreads();
        // writeback sorted records for gatherA layer-2
        for (int i = t; i < cnt; i += 512) staged_e[beg + i] = sm.e.lsort[i];
        // fused gatherA layer-1: 32 edges x 16 lanes, records from LDS
        int el = t >> 4, j = t & 15;
        int lo = sm.e.lbeg[el], hi = lo + sm.e.hist[el];
        float acc = 0.f;
        int k = lo;
        for (; k + 4 <= hi; k += 4) {           // 4-deep MLP
            int r0 = sm.e.lsort[k]     & 0x1FFFF;
            int r1 = sm.e.lsort[k + 1] & 0x1FFFF;
            int r2 = sm.e.lsort[k + 2] & 0x1FFFF;
            int r3 = sm.e.lsort[k + 3] & 0x1FFFF;
            float t0 = T[(size_t)r0 * D_H + j];
            float t1 = T[(size_t)r1 * D_H + j];
            float t2 = T[(size_t)r2 * D_H + j];
            float t3 = T[(size_t)r3 * D_H + j];
            acc += t0; acc += t1; acc += t2; acc += t3;
        }
        for (; k < hi; ++k) acc += T[(size_t)(sm.e.lsort[k] & 0x1FFFF) * D_H + j];
        // denominator: lanes split the w-gather, xor-reduce within 16-cluster
        float den = 0.f;
        for (int k2 = lo + j; k2 < hi; k2 += 16) den += w[sm.e.lsort[k2] & 0x1FFFF];
#pragma unroll
        for (int o = 1; o < 16; o <<= 1) den += __shfl_xor(den, o, 64);
        int e = b * EBS + el;                    // 625*32 == 20000 exactly
        e_feat[(size_t)e * D_H + j] = acc / fmaxf(den, 1e-6f);
        if (j == 0) e_den[e] = den;
    } else {
        int b = blockIdx.x - NBE;
        int beg = b * VCAP, cnt = min(cnt_bv[b], VCAP);
        for (int i = t; i < VBS; i += 512) sm.v.hist[i] = 0;
        __syncthreads();
        int rec[5], key[5], nr = 0;
#pragma unroll
        for (int r = 0; r < 5; ++r) {
            int k = r * 512 + t;
            if (k < cnt) {
                rec[nr] = staged_v[beg + k];
                key[nr] = (rec[nr] >> 15) & 255;
                atomicAdd(&sm.v.hist[key[nr]], 1);
                ++nr;
            }
        }
        __syncthreads();
        int hh = (t < VBS) ? sm.v.hist[t] : 0;
        int ex = block_exscan512(hh, sm.v.sc);
        if (t < VBS) {
            sm.v.cursor[t] = ex;
            int n = b * VBS + t;
            if (n < N_NODES) off_v2[n] = make_int2(beg + ex, beg + ex + hh);
        }
        __syncthreads();
        for (int r = 0; r < nr; ++r) {
            int p = atomicAdd(&sm.v.cursor[key[r]], 1);
            sm.v.lsort[p] = rec[r];
        }
        __syncthreads();
        for (int i = t; i < cnt; i += 512) staged_v[beg + i] = sm.v.lsort[i];
    }
}

// ---------------- K3: gatherB layer 1: 4 lanes/node, relu(mean+b1)*w ------------
__global__ __launch_bounds__(512) void gatherB1_kernel(
    const int2* __restrict__ off_v2, const int* __restrict__ staged_v,
    const float* __restrict__ e_feat, const float* __restrict__ w,
    const float* __restrict__ b1, float* __restrict__ out) {
    int t = blockIdx.x * 512 + threadIdx.x;
    int n = t >> 2;
    if (n >= N_NODES) return;
    int c = (t & 3) << 2;
    int2 be = off_v2[n];
    f32x4 acc = {0.f, 0.f, 0.f, 0.f};
    for (int k = be.x; k < be.y; ++k) {
        int e = staged_v[k] & 0x7FFF;
        acc += *(const f32x4*)(e_feat + (size_t)e * D_H + c);
    }
    float inv = 1.f / fmaxf((float)(be.y - be.x), 1.f);
    f32x4 bb = *(const f32x4*)(b1 + c);
    float wn = w[n];
    f32x4 r;
#pragma unroll
    for (int i = 0; i < 4; ++i) r[i] = fmaxf(acc[i] * inv + bb[i], 0.f) * wn;
    *(f32x4*)(out + (size_t)n * D_H + c) = r;
}

// ---------------- K4: gatherA layer-2 (reuses e_den, sorted staged_e) -----------
__global__ __launch_bounds__(512) void gatherA2_kernel(
    const int2* __restrict__ off_e2, const int* __restrict__ staged_e,
    const float* __restrict__ X, const float* __restrict__ e_den,
    float* __restrict__ e_feat) {
    int e = (blockIdx.x * 512 + threadIdx.x) >> 6;
    if (e >= N_EDGES) return;
    int lane = threadIdx.x & 63;
    int g = lane >> 2, c = (lane & 3) << 2;
    int2 be = off_e2[e];
    f32x4 acc = {0.f, 0.f, 0.f, 0.f};
    for (int k = be.x + g; k < be.y; k += 16) {
        int rec = staged_e[k];
        int v = rec & 0x1FFFF;
        acc += *(const f32x4*)(X + (size_t)v * D_H + c);
    }
#pragma unroll
    for (int s = 4; s <= 32; s <<= 1) {
        acc[0] += __shfl_xor(acc[0], s, 64);
        acc[1] += __shfl_xor(acc[1], s, 64);
        acc[2] += __shfl_xor(acc[2], s, 64);
        acc[3] += __shfl_xor(acc[3], s, 64);
    }
    if (lane < 4) {
        float inv = 1.f / fmaxf(e_den[e], 1e-6f);
        f32x4 r = acc * inv;
        *(f32x4*)(e_feat + (size_t)e * D_H + c) = r;
    }
}

// ---------------- K5: gatherB layer 2 + W2 matmul + log_softmax -----------------
__global__ __launch_bounds__(512) void gatherB2_final_kernel(
    const int2* __restrict__ off_v2, const int* __restrict__ staged_v,
    const float* __restrict__ e_feat,
    const float* __restrict__ W2, const float* __restrict__ b2,
    float* __restrict__ out) {
    __shared__ float sy[128 * 20];
    __shared__ float sW2[D_H * D_OUT];
    __shared__ float sb2[D_OUT];
    int t = threadIdx.x;
    for (int i = t; i < D_H * D_OUT; i += 512) sW2[i] = W2[i];
    if (t < D_OUT) sb2[t] = b2[t];
    int nl = t >> 2, c = (t & 3) << 2;
    int n = blockIdx.x * 128 + nl;
    f32x4 y = {0.f, 0.f, 0.f, 0.f};
    if (n < N_NODES) {
        int2 be = off_v2[n];
        f32x4 acc = {0.f, 0.f, 0.f, 0.f};
        for (int k = be.x; k < be.y; ++k) {
            int e = staged_v[k] & 0x7FFF;
            acc += *(const f32x4*)(e_feat + (size_t)e * D_H + c);
        }
        float inv = 1.f / fmaxf((float)(be.y - be.x), 1.f);
        y = acc * inv;
    }
    *(f32x4*)(sy + nl * 20 + c) = y;
    __syncthreads();
    if (n >= N_NODES) return;
    int c0 = (t & 3) * 10;
    float z[10];
#pragma unroll
    for (int i = 0; i < 10; ++i) z[i] = sb2[c0 + i];
#pragma unroll
    for (int jj = 0; jj < D_H; ++jj) {
        float yy = sy[nl * 20 + jj];
#pragma unroll
        for (int i = 0; i < 10; ++i) z[i] += yy * sW2[jj * D_OUT + c0 + i];
    }
    float m = z[0];
#pragma unroll
    for (int i = 1; i < 10; ++i) m = fmaxf(m, z[i]);
    m = fmaxf(m, __shfl_xor(m, 1, 64));
    m = fmaxf(m, __shfl_xor(m, 2, 64));
    float se = 0.f;
#pragma unroll
    for (int i = 0; i < 10; ++i) se += __expf(z[i] - m);
    se += __shfl_xor(se, 1, 64);
    se += __shfl_xor(se, 2, 64);
    float lse = m + __logf(se);
    float* op = out + (size_t)n * D_OUT + c0;
#pragma unroll
    for (int i = 0; i < 10; ++i) op[i] = z[i] - lse;
}

extern "C" void kernel_launch(void* const* d_in, const int* in_sizes, int n_in,
                              void* d_out, int out_size, void* d_ws, size_t ws_size,
                              hipStream_t stream) {
    const float* H  = (const float*)d_in[0];
    const float* w  = (const float*)d_in[1];
    const int*   ni = (const int*)d_in[2];
    const int*   ei = (const int*)d_in[3];
    const float* W1 = (const float*)d_in[4];
    const float* b1 = (const float*)d_in[5];
    const float* W2 = (const float*)d_in[6];
    const float* b2 = (const float*)d_in[7];
    float* out = (float*)d_out;

    // workspace layout (4-byte words)
    int*            ws_i     = (int*)d_ws;
    int*            cnt_be   = ws_i + 0;                      // 625
    int*            cnt_bv   = ws_i + 640;                    // 392
    unsigned short* bfrag    = (unsigned short*)(ws_i + 1040);// 4096 ush = 2048 w
    int2*           off_e2   = (int2*)(ws_i + 3088);          // 20000 int2
    int2*           off_v2   = (int2*)(ws_i + 43088);         // 100000 int2
    int*            staged_e = ws_i + 243088;                 // 625*1600
    int*            staged_v = ws_i + 1243088;                // 392*2400
    float*          e_den    = (float*)(ws_i + 2183888);      // 20000
    float*          T        = (float*)(ws_i + 2203888);      // 1,600,000
    float*          e_feat   = (float*)(ws_i + 3803888);      // 320,000
    float*          x1       = (float*)(ws_i + 4123888);      // 1,600,000
    // total 5,723,888 words = 22.9 MB

    init_kernel<<<1, 512, 0, stream>>>(W1, bfrag, cnt_be);

    part_gemm_kernel<<<GRID_K1, 512, 0, stream>>>(
        ni, ei, w, cnt_be, cnt_bv, staged_e, staged_v, H, bfrag, T);

    // edge sort + fused layer-1 edge aggregation || node sort
    sortE_gA1_sortN_kernel<<<NBE + NBV, 512, 0, stream>>>(
        cnt_be, staged_e, off_e2, cnt_bv, staged_v, off_v2, T, w, e_den, e_feat);

    gatherB1_kernel<<<782, 512, 0, stream>>>(off_v2, staged_v, e_feat, w, b1, x1);

    gatherA2_kernel<<<2500, 512, 0, stream>>>(off_e2, staged_e, x1, e_den, e_feat);

    gatherB2_final_kernel<<<782, 512, 0, stream>>>(
        off_v2, staged_v, e_feat, W2, b2, out);
}